// Round 3
// baseline (1512.819 us; speedup 1.0000x reference)
//
#include <hip/hip_runtime.h>
#include <hip/hip_bf16.h>

#define NN 12288
#define NE 196608
#define HD 128
#define ZD 128
#define NEGV (-1.0e9f)
#define SEG 8
#define SEG_U (NN / SEG)            // 1536
#define TILES_PER_SEG (SEG_U / 64)  // 24

// Stable top-2 merge: total order by (value desc, index asc) — associative,
// reproduces jax.lax.top_k stable tie-breaking regardless of merge order.
__device__ __forceinline__ void top2_merge(float s, int u, float& v1, int& i1,
                                           float& v2, int& i2) {
    if (s > v1 || (s == v1 && u < i1)) { v2 = v1; i2 = i1; v1 = s; i1 = u; }
    else if (s > v2 || (s == v2 && u < i2)) { v2 = s; i2 = u; }
}

__global__ __launch_bounds__(256) void k_deg_init(int* degi) {
    int i = blockIdx.x * 256 + threadIdx.x;
    degi[i] = 1;  // self-loop
}

__global__ __launch_bounds__(256) void k_deg_count(const int* __restrict__ edst,
                                                   int* degi) {
    int e = blockIdx.x * 256 + threadIdx.x;
    atomicAdd(&degi[edst[e]], 1);
}

__global__ __launch_bounds__(256) void k_inv_agg2(const int* __restrict__ degi,
                                                  const float* __restrict__ x,
                                                  float* inv, float* agg2) {
    int i = blockIdx.x * 256 + threadIdx.x;
    float iv = rsqrtf((float)degi[i]);  // deg >= 1 always
    inv[i] = iv;
    float w = iv * iv;                  // self-loop weight
    agg2[2 * i]     = x[2 * i] * w;
    agg2[2 * i + 1] = x[2 * i + 1] * w;
}

__global__ __launch_bounds__(256) void k_scatter2(const int* __restrict__ esrc,
                                                  const int* __restrict__ edst,
                                                  const float* __restrict__ x,
                                                  const float* __restrict__ inv,
                                                  float* agg2) {
    int e = blockIdx.x * 256 + threadIdx.x;
    int u = esrc[e], v = edst[e];
    float w = inv[u] * inv[v];
    atomicAdd(&agg2[2 * v],     x[2 * u] * w);
    atomicAdd(&agg2[2 * v + 1], x[2 * u + 1] * w);
}

// h1 = relu(agg2 @ W1 + b1); also seed aggH with the layer-2 self-loop term.
__global__ __launch_bounds__(256) void k_lin1(const float* __restrict__ agg2,
                                              const float* __restrict__ W1,
                                              const float* __restrict__ b1,
                                              const float* __restrict__ inv,
                                              float* h1, float* aggH) {
    int t = blockIdx.x * 256 + threadIdx.x;
    int v = t >> 7, j = t & 127;
    float hv = fmaxf(fmaf(agg2[2 * v], W1[j],
                     fmaf(agg2[2 * v + 1], W1[HD + j], b1[j])), 0.f);
    h1[t] = hv;
    float iv = inv[v];
    aggH[t] = hv * iv * iv;
}

// 2 edges per 256-thread block; 128 lanes per edge; atomic scatter into aggH.
__global__ __launch_bounds__(256) void k_scatterH(const int* __restrict__ esrc,
                                                  const int* __restrict__ edst,
                                                  const float* __restrict__ inv,
                                                  const float* __restrict__ h1,
                                                  float* aggH) {
    int tid = threadIdx.x;
    int e = blockIdx.x * 2 + (tid >> 7);
    int j = tid & 127;
    int u = esrc[e], v = edst[e];
    float w = inv[u] * inv[v];
    atomicAdd(&aggH[(size_t)v * HD + j], h1[(size_t)u * HD + j] * w);
}

// cz1 = z @ Wm1[128:256] + bm1 ; cz2 = z @ Wi1[256:384] + bi1
__global__ __launch_bounds__(256) void k_zvec(const float* __restrict__ z,
                                              const float* __restrict__ Wm1,
                                              const float* __restrict__ bm1,
                                              const float* __restrict__ Wi1,
                                              const float* __restrict__ bi1,
                                              float* cz1, float* cz2) {
    int tid = threadIdx.x;
    int j = tid & 127;
    if (tid < 128) {
        float a = bm1[j];
        for (int k = 0; k < ZD; ++k) a = fmaf(z[k], Wm1[(HD + k) * HD + j], a);
        cz1[j] = a;
    } else {
        float a = bi1[j];
        for (int k = 0; k < ZD; ++k) a = fmaf(z[k], Wi1[(2 * HD + k) * HD + j], a);
        cz2[j] = a;
    }
}

// Generic N x 128 @ 128 x 128 (+bias)(+relu). 16 rows/block, 256 threads.
// IN-PLACE SAFE (out may equal in): each block stages its 16 rows into LDS
// before the barrier and only writes the rows it staged.
__global__ __launch_bounds__(256) void k_rowmm(const float* __restrict__ in,
                                               const float* __restrict__ W,
                                               const float* __restrict__ bias,
                                               float* __restrict__ out,
                                               int do_relu) {
    __shared__ float4 ins4[16 * 32];
    int tid = threadIdx.x;
    int r0 = blockIdx.x * 16;
    const float4* src4 = (const float4*)(in + (size_t)r0 * HD);
#pragma unroll
    for (int i = 0; i < 2; ++i) ins4[tid + i * 256] = src4[tid + i * 256];
    __syncthreads();
    int j = tid & 127;
    int rg = tid >> 7;  // 0..1
    float acc[8];
#pragma unroll
    for (int r = 0; r < 8; ++r) acc[r] = 0.f;
    for (int k4 = 0; k4 < 32; ++k4) {
        int k = k4 * 4;
        float w0 = W[(k + 0) * HD + j];
        float w1 = W[(k + 1) * HD + j];
        float w2 = W[(k + 2) * HD + j];
        float w3 = W[(k + 3) * HD + j];
#pragma unroll
        for (int r = 0; r < 8; ++r) {
            float4 iv = ins4[(rg * 8 + r) * 32 + k4];
            acc[r] = fmaf(iv.x, w0, acc[r]);
            acc[r] = fmaf(iv.y, w1, acc[r]);
            acc[r] = fmaf(iv.z, w2, acc[r]);
            acc[r] = fmaf(iv.w, w3, acc[r]);
        }
    }
    float bv = bias ? bias[j] : 0.f;
#pragma unroll
    for (int r = 0; r < 8; ++r) {
        float v = acc[r] + bv;
        if (do_relu) v = fmaxf(v, 0.f);
        out[(size_t)(r0 + rg * 8 + r) * HD + j] = v;
    }
}

// Fused scores + masked stable top-2. Block: 64 target rows; grid.y splits the
// candidate range into SEG segments. 256 threads = 16x16, 4x4 micro-tile.
// LDS tiles are column-rotation-swizzled ((c4+row)&31) to spread banks.
__global__ __launch_bounds__(256) void k_score_top2(const float* __restrict__ ht,
                                                    const float* __restrict__ hs,
                                                    const int* __restrict__ depth,
                                                    float* __restrict__ pv,
                                                    int* __restrict__ pi) {
    __shared__ float4 As4[64 * 32];
    __shared__ float4 Bs4[64 * 32];
    int tid = threadIdx.x;
    int row0 = blockIdx.x * 64;
    int seg = blockIdx.y;
    int u_base = seg * SEG_U;
    int tx = tid & 15, ty = tid >> 4;

    {  // load A tile (swizzled)
        const float4* s4 = (const float4*)(ht + (size_t)row0 * HD);
        #pragma unroll
        for (int i = 0; i < 8; ++i) {
            int q = tid + i * 256;
            int r = q >> 5, c4 = q & 31;
            As4[r * 32 + ((c4 + r) & 31)] = s4[q];
        }
    }
    int dvr[4];
#pragma unroll
    for (int mi = 0; mi < 4; ++mi) dvr[mi] = depth[row0 + ty * 4 + mi];

    float v1[4], v2[4];
    int i1[4], i2[4];
#pragma unroll
    for (int mi = 0; mi < 4; ++mi) {
        v1[mi] = v2[mi] = -3.4e38f;
        i1[mi] = i2[mi] = 0x7fffffff;
    }

    for (int t = 0; t < TILES_PER_SEG; ++t) {
        int u0 = u_base + t * 64;
        __syncthreads();
        {  // load B tile (swizzled)
            const float4* s4 = (const float4*)(hs + (size_t)u0 * HD);
            #pragma unroll
            for (int i = 0; i < 8; ++i) {
                int q = tid + i * 256;
                int r = q >> 5, c4 = q & 31;
                Bs4[r * 32 + ((c4 + r) & 31)] = s4[q];
            }
        }
        __syncthreads();

        float acc[4][4];
#pragma unroll
        for (int mi = 0; mi < 4; ++mi)
#pragma unroll
            for (int ni = 0; ni < 4; ++ni) acc[mi][ni] = 0.f;

        for (int k4 = 0; k4 < 32; ++k4) {
            float4 a[4], b[4];
#pragma unroll
            for (int mi = 0; mi < 4; ++mi) {
                int r = ty * 4 + mi;
                a[mi] = As4[r * 32 + ((k4 + r) & 31)];
            }
#pragma unroll
            for (int ni = 0; ni < 4; ++ni) {
                int r = tx * 4 + ni;
                b[ni] = Bs4[r * 32 + ((k4 + r) & 31)];
            }
#pragma unroll
            for (int mi = 0; mi < 4; ++mi)
#pragma unroll
                for (int ni = 0; ni < 4; ++ni) {
                    acc[mi][ni] = fmaf(a[mi].x, b[ni].x, acc[mi][ni]);
                    acc[mi][ni] = fmaf(a[mi].y, b[ni].y, acc[mi][ni]);
                    acc[mi][ni] = fmaf(a[mi].z, b[ni].z, acc[mi][ni]);
                    acc[mi][ni] = fmaf(a[mi].w, b[ni].w, acc[mi][ni]);
                }
        }
        // mask + running top-2 (masked entries fed as exactly NEGV: index
        // tie-breaking for rows with <2 real candidates must match jax)
#pragma unroll
        for (int ni = 0; ni < 4; ++ni) {
            int u = u0 + tx * 4 + ni;
            int du = depth[u];
#pragma unroll
            for (int mi = 0; mi < 4; ++mi) {
                float s = (du < dvr[mi]) ? acc[mi][ni] : NEGV;
                top2_merge(s, u, v1[mi], i1[mi], v2[mi], i2[mi]);
            }
        }
    }
    __syncthreads();
    // cross-thread merge over tx, reusing Bs as scratch
    float* mv1 = (float*)Bs4;
    float* mv2 = mv1 + 1024;
    int* mi1 = (int*)(mv1 + 2048);
    int* mi2 = (int*)(mv1 + 3072);
#pragma unroll
    for (int mi = 0; mi < 4; ++mi) {
        int m = ty * 4 + mi;
        mv1[m * 16 + tx] = v1[mi];
        mv2[m * 16 + tx] = v2[mi];
        mi1[m * 16 + tx] = i1[mi];
        mi2[m * 16 + tx] = i2[mi];
    }
    __syncthreads();
    if (tid < 64) {
        float V1 = -3.4e38f, V2 = -3.4e38f;
        int I1 = 0x7fffffff, I2 = 0x7fffffff;
        for (int t = 0; t < 16; ++t) {
            top2_merge(mv1[tid * 16 + t], mi1[tid * 16 + t], V1, I1, V2, I2);
            top2_merge(mv2[tid * 16 + t], mi2[tid * 16 + t], V1, I1, V2, I2);
        }
        size_t o = ((size_t)seg * NN + row0 + tid) * 2;
        pv[o] = V1; pv[o + 1] = V2;
        pi[o] = I1; pi[o + 1] = I2;
    }
}

// ONE kernel writes ALL outputs (as FLOAT32 — reference output dtype is f32):
// per node v (one wave each), merge the 8 segment partials (redundantly on
// every lane — broadcast loads), emit vals/idx/edge_valid, then run the
// inversion MLP for both candidate pairs.
__global__ __launch_bounds__(256) void k_final(const float* __restrict__ pv,
                                               const int* __restrict__ pi,
                                               const int* __restrict__ ntype,
                                               const int* __restrict__ ndepth,
                                               const float* __restrict__ A,
                                               const float* __restrict__ B,
                                               const float* __restrict__ Wi2,
                                               const float* __restrict__ bi2,
                                               float* __restrict__ out) {
    int tid = threadIdx.x;
    int lane = tid & 63;
    int v = blockIdx.x * 4 + (tid >> 6);

    float V1 = -3.4e38f, V2 = -3.4e38f;
    int I1 = 0x7fffffff, I2 = 0x7fffffff;
#pragma unroll
    for (int s = 0; s < SEG; ++s) {
        size_t o = ((size_t)s * NN + v) * 2;
        top2_merge(pv[o],     pi[o],     V1, I1, V2, I2);
        top2_merge(pv[o + 1], pi[o + 1], V1, I1, V2, I2);
    }

    if (lane == 0) {
        int tp = ntype[v];
        bool tv = (tp != 0) && (ndepth[v] > 0) && (V1 > -5.0e8f);  // NEG/2
        out[2 * NN + 2 * v]     = V1;
        out[2 * NN + 2 * v + 1] = V2;
        out[4 * NN + 2 * v]     = (float)I1;
        out[4 * NN + 2 * v + 1] = (float)I2;
        out[6 * NN + 2 * v]     = tv ? 1.f : 0.f;
        out[6 * NN + 2 * v + 1] = (tv && tp == 2) ? 1.f : 0.f;
    }

    // inversion MLP: logit = relu(A[u] + B[v]) . Wi2 + bi2, 2 elems per lane
    const float2* B2 = (const float2*)B;
    const float2* W2v = (const float2*)Wi2;
    float2 bv = B2[(size_t)v * 64 + lane];
    float2 wv = W2v[lane];
    float bias = bi2[0];
#pragma unroll
    for (int j = 0; j < 2; ++j) {
        int u = (j == 0) ? I1 : I2;
        u = min(max(u, 0), NN - 1);  // defensive clamp (no-op when correct)
        float2 av = ((const float2*)A)[(size_t)u * 64 + lane];
        float h0 = fmaxf(av.x + bv.x, 0.f);
        float h1 = fmaxf(av.y + bv.y, 0.f);
        float acc = fmaf(h0, wv.x, h1 * wv.y);
        for (int off = 32; off > 0; off >>= 1) acc += __shfl_down(acc, off);
        if (lane == 0) {
            float logit = acc + bias;
            out[2 * v + j] = 1.f / (1.f + expf(-logit));
        }
    }
}

extern "C" void kernel_launch(void* const* d_in, const int* in_sizes, int n_in,
                              void* d_out, int out_size, void* d_ws, size_t ws_size,
                              hipStream_t stream) {
    (void)in_sizes; (void)n_in; (void)out_size; (void)ws_size;
    const float* x   = (const float*)d_in[0];
    const float* z   = (const float*)d_in[1];
    const int* ntype = (const int*)d_in[2];
    const int* ndep  = (const int*)d_in[3];
    const int* eidx  = (const int*)d_in[4];
    const float* W1  = (const float*)d_in[5];
    const float* b1  = (const float*)d_in[6];
    const float* W2  = (const float*)d_in[7];
    const float* b2  = (const float*)d_in[8];
    const float* Wm1 = (const float*)d_in[9];
    const float* bm1 = (const float*)d_in[10];
    const float* Wm2 = (const float*)d_in[11];
    const float* bm2 = (const float*)d_in[12];
    const float* Wsm = (const float*)d_in[13];
    const float* Wtm = (const float*)d_in[14];
    const float* Wi1 = (const float*)d_in[15];
    const float* bi1 = (const float*)d_in[16];
    const float* Wi2 = (const float*)d_in[17];
    const float* bi2 = (const float*)d_in[18];
    float* out = (float*)d_out;

    const int* esrc = eidx;
    const int* edst = eidx + NE;

    // Workspace layout (floats), partials FIRST, big buffers LAST. ~20.6 MiB.
    float* ws = (float*)d_ws;
    float* pv   = ws;                                  // [SEG*2*NN]
    int*   pi   = (int*)(pv + (size_t)SEG * 2 * NN);   // [SEG*2*NN]
    int*   degi = (int*)(pv + (size_t)2 * SEG * 2 * NN);  // [N]
    float* inv  = (float*)degi + NN;                   // [N]
    float* agg2 = inv + NN;                            // [2N]
    float* cz1  = agg2 + 2 * NN;                       // [128]
    float* cz2  = cz1 + 128;                           // [128]
    size_t F = (size_t)NN * HD;
    float* s0 = cz2 + 128;   // h1 -> ht -> (dead)
    float* s1 = s0 + F;      // aggH -> h2 -> t -> h -> B   (in-place chain)
    float* s2 = s1 + F;      // hs -> A

    k_deg_init<<<NN / 256, 256, 0, stream>>>(degi);
    k_deg_count<<<NE / 256, 256, 0, stream>>>(edst, degi);
    k_inv_agg2<<<NN / 256, 256, 0, stream>>>(degi, x, inv, agg2);
    k_scatter2<<<NE / 256, 256, 0, stream>>>(esrc, edst, x, inv, agg2);
    k_lin1<<<NN * HD / 256, 256, 0, stream>>>(agg2, W1, b1, inv, s0, s1);
    k_scatterH<<<NE / 2, 256, 0, stream>>>(esrc, edst, inv, s0, s1);
    k_zvec<<<1, 256, 0, stream>>>(z, Wm1, bm1, Wi1, bi1, cz1, cz2);
    k_rowmm<<<NN / 16, 256, 0, stream>>>(s1, W2, b2, s1, 1);              // h2 (in-place)
    k_rowmm<<<NN / 16, 256, 0, stream>>>(s1, Wm1, cz1, s1, 1);            // t  (in-place)
    k_rowmm<<<NN / 16, 256, 0, stream>>>(s1, Wm2, bm2, s1, 0);            // h  (in-place)
    k_rowmm<<<NN / 16, 256, 0, stream>>>(s1, Wtm, nullptr, s0, 0);        // ht
    k_rowmm<<<NN / 16, 256, 0, stream>>>(s1, Wsm, nullptr, s2, 0);        // hs
    k_score_top2<<<dim3(NN / 64, SEG), 256, 0, stream>>>(s0, s2, ndep, pv, pi);
    k_rowmm<<<NN / 16, 256, 0, stream>>>(s1, Wi1, nullptr, s2, 0);        // A (hs dead)
    k_rowmm<<<NN / 16, 256, 0, stream>>>(s1, Wi1 + HD * HD, cz2, s1, 0);  // B (in-place)
    k_final<<<NN / 4, 256, 0, stream>>>(pv, pi, ntype, ndep, s2, s1, Wi2, bi2, out);
}

// Round 4
// 787.496 us; speedup vs baseline: 1.9210x; 1.9210x over previous
//
#include <hip/hip_runtime.h>
#include <hip/hip_bf16.h>

#define NN 12288
#define NE 196608
#define HD 128
#define ZD 128
#define NEGV (-1.0e9f)
#define SEG 8
#define SEG_U (NN / SEG)            // 1536
#define TILES_PER_SEG (SEG_U / 64)  // 24

using s8v = __attribute__((ext_vector_type(8))) short;  // 8 bf16 = 4 VGPRs
using f4v = __attribute__((ext_vector_type(4))) float;  // 4 fp32 acc

// Stable top-2 merge: total order by (value desc, index asc) — associative,
// reproduces jax.lax.top_k stable tie-breaking regardless of merge order.
__device__ __forceinline__ void top2_merge(float s, int u, float& v1, int& i1,
                                           float& v2, int& i2) {
    if (s > v1 || (s == v1 && u < i1)) { v2 = v1; i2 = i1; v1 = s; i1 = u; }
    else if (s > v2 || (s == v2 && u < i2)) { v2 = s; i2 = u; }
}

__global__ __launch_bounds__(256) void k_deg_init(int* degi) {
    int i = blockIdx.x * 256 + threadIdx.x;
    degi[i] = 1;  // self-loop
}

__global__ __launch_bounds__(256) void k_deg_count(const int* __restrict__ edst,
                                                   int* degi) {
    int e = blockIdx.x * 256 + threadIdx.x;
    atomicAdd(&degi[edst[e]], 1);
}

__global__ __launch_bounds__(256) void k_inv_agg2(const int* __restrict__ degi,
                                                  const float* __restrict__ x,
                                                  float* inv, float* agg2) {
    int i = blockIdx.x * 256 + threadIdx.x;
    float iv = rsqrtf((float)degi[i]);  // deg >= 1 always
    inv[i] = iv;
    float w = iv * iv;                  // self-loop weight
    agg2[2 * i]     = x[2 * i] * w;
    agg2[2 * i + 1] = x[2 * i + 1] * w;
}

__global__ __launch_bounds__(256) void k_scatter2(const int* __restrict__ esrc,
                                                  const int* __restrict__ edst,
                                                  const float* __restrict__ x,
                                                  const float* __restrict__ inv,
                                                  float* agg2) {
    int e = blockIdx.x * 256 + threadIdx.x;
    int u = esrc[e], v = edst[e];
    float w = inv[u] * inv[v];
    atomicAdd(&agg2[2 * v],     x[2 * u] * w);
    atomicAdd(&agg2[2 * v + 1], x[2 * u + 1] * w);
}

// h1 = relu(agg2 @ W1 + b1); also seed aggH with the layer-2 self-loop term.
__global__ __launch_bounds__(256) void k_lin1(const float* __restrict__ agg2,
                                              const float* __restrict__ W1,
                                              const float* __restrict__ b1,
                                              const float* __restrict__ inv,
                                              float* h1, float* aggH) {
    int t = blockIdx.x * 256 + threadIdx.x;
    int v = t >> 7, j = t & 127;
    float hv = fmaxf(fmaf(agg2[2 * v], W1[j],
                     fmaf(agg2[2 * v + 1], W1[HD + j], b1[j])), 0.f);
    h1[t] = hv;
    float iv = inv[v];
    aggH[t] = hv * iv * iv;
}

// 2 edges per 256-thread block; 128 lanes per edge; atomic scatter into aggH.
__global__ __launch_bounds__(256) void k_scatterH(const int* __restrict__ esrc,
                                                  const int* __restrict__ edst,
                                                  const float* __restrict__ inv,
                                                  const float* __restrict__ h1,
                                                  float* aggH) {
    int tid = threadIdx.x;
    int e = blockIdx.x * 2 + (tid >> 7);
    int j = tid & 127;
    int u = esrc[e], v = edst[e];
    float w = inv[u] * inv[v];
    atomicAdd(&aggH[(size_t)v * HD + j], h1[(size_t)u * HD + j] * w);
}

// cz1 = z @ Wm1[128:256] + bm1 ; cz2 = z @ Wi1[256:384] + bi1
__global__ __launch_bounds__(256) void k_zvec(const float* __restrict__ z,
                                              const float* __restrict__ Wm1,
                                              const float* __restrict__ bm1,
                                              const float* __restrict__ Wi1,
                                              const float* __restrict__ bi1,
                                              float* cz1, float* cz2) {
    int tid = threadIdx.x;
    int j = tid & 127;
    if (tid < 128) {
        float a = bm1[j];
        for (int k = 0; k < ZD; ++k) a = fmaf(z[k], Wm1[(HD + k) * HD + j], a);
        cz1[j] = a;
    } else {
        float a = bi1[j];
        for (int k = 0; k < ZD; ++k) a = fmaf(z[k], Wi1[(2 * HD + k) * HD + j], a);
        cz2[j] = a;
    }
}

// Generic N x 128 @ 128 x 128 (+bias)(+relu). 16 rows/block, 256 threads.
// IN-PLACE SAFE (out may equal in): each block stages its 16 rows into LDS
// before the barrier and only writes the rows it staged.
// If outb != nullptr, writes bf16 (rte) to outb instead of f32 to out.
__global__ __launch_bounds__(256) void k_rowmm(const float* __restrict__ in,
                                               const float* __restrict__ W,
                                               const float* __restrict__ bias,
                                               float* __restrict__ out,
                                               __hip_bfloat16* __restrict__ outb,
                                               int do_relu) {
    __shared__ float4 ins4[16 * 32];
    int tid = threadIdx.x;
    int r0 = blockIdx.x * 16;
    const float4* src4 = (const float4*)(in + (size_t)r0 * HD);
#pragma unroll
    for (int i = 0; i < 2; ++i) ins4[tid + i * 256] = src4[tid + i * 256];
    __syncthreads();
    int j = tid & 127;
    int rg = tid >> 7;  // 0..1
    float acc[8];
#pragma unroll
    for (int r = 0; r < 8; ++r) acc[r] = 0.f;
    for (int k4 = 0; k4 < 32; ++k4) {
        int k = k4 * 4;
        float w0 = W[(k + 0) * HD + j];
        float w1 = W[(k + 1) * HD + j];
        float w2 = W[(k + 2) * HD + j];
        float w3 = W[(k + 3) * HD + j];
#pragma unroll
        for (int r = 0; r < 8; ++r) {
            float4 iv = ins4[(rg * 8 + r) * 32 + k4];
            acc[r] = fmaf(iv.x, w0, acc[r]);
            acc[r] = fmaf(iv.y, w1, acc[r]);
            acc[r] = fmaf(iv.z, w2, acc[r]);
            acc[r] = fmaf(iv.w, w3, acc[r]);
        }
    }
    float bv = bias ? bias[j] : 0.f;
#pragma unroll
    for (int r = 0; r < 8; ++r) {
        float v = acc[r] + bv;
        if (do_relu) v = fmaxf(v, 0.f);
        size_t o = (size_t)(r0 + rg * 8 + r) * HD + j;
        if (outb) outb[o] = __float2bfloat16(v);
        else      out[o] = v;
    }
}

// Fused bf16-MFMA scores + masked stable top-2.
// Block: 64 target rows x 64-candidate stream over one segment. 4 waves:
// wave w owns target rows [w*16, w*16+16) and iterates 4 n-subtiles.
// mfma_f32_16x16x32_bf16 layouts (HW-verified m89/m91/m120):
//   A[m=lane&15][k=(lane>>4)*8+j]  (8 contiguous bf16 = one 16B chunk)
//   B^T[n=lane&15][k=(lane>>4)*8+j] (hs is [n][k] row-major -> same pattern)
//   C/D: col(n)=lane&15, row(m)=(lane>>4)*4+reg
// LDS tiles stored as 16B chunks at [row*16 + (c ^ (row&7))] — XOR swizzle
// gives uniform bank-quad spread for both staging stores and frag reads.
__global__ __launch_bounds__(256) void k_score_top2_mfma(
        const __hip_bfloat16* __restrict__ htb,
        const __hip_bfloat16* __restrict__ hsb,
        const int* __restrict__ depth,
        float* __restrict__ pv, int* __restrict__ pi) {
    __shared__ s8v As[64 * 16];  // 16 KB
    __shared__ s8v Bs[64 * 16];  // 16 KB
    int tid = threadIdx.x;
    int w = tid >> 6;       // wave -> m-block (16 rows)
    int l = tid & 63;
    int lane16 = l & 15;
    int quad = l >> 4;      // 0..3
    int row0 = blockIdx.x * 64;
    int seg = blockIdx.y;
    int u_base = seg * SEG_U;

    {  // stage A tile (64 rows x 16 chunks), swizzled
        const s8v* g = (const s8v*)(htb + (size_t)row0 * HD);
#pragma unroll
        for (int i = 0; i < 4; ++i) {
            int q = tid + i * 256;
            int r = q >> 4, c = q & 15;
            As[r * 16 + (c ^ (r & 7))] = g[q];
        }
    }

    int dvr[4];  // depths of the 4 rows this lane owns (row = quad*4+reg)
#pragma unroll
    for (int r = 0; r < 4; ++r) dvr[r] = depth[row0 + w * 16 + quad * 4 + r];

    float v1[4], v2[4];
    int i1[4], i2[4];
#pragma unroll
    for (int r = 0; r < 4; ++r) {
        v1[r] = v2[r] = -3.4e38f;
        i1[r] = i2[r] = 0x7fffffff;
    }

    int ar = w * 16 + lane16;  // A tile row this lane reads

    for (int t = 0; t < TILES_PER_SEG; ++t) {
        int u0 = u_base + t * 64;
        __syncthreads();  // Bs from previous tile fully consumed
        {  // stage B tile, swizzled
            const s8v* g = (const s8v*)(hsb + (size_t)u0 * HD);
#pragma unroll
            for (int i = 0; i < 4; ++i) {
                int q = tid + i * 256;
                int r = q >> 4, c = q & 15;
                Bs[r * 16 + (c ^ (r & 7))] = g[q];
            }
        }
        __syncthreads();

        f4v acc[4];
#pragma unroll
        for (int nb = 0; nb < 4; ++nb) acc[nb] = (f4v){0.f, 0.f, 0.f, 0.f};

#pragma unroll
        for (int kc = 0; kc < 4; ++kc) {      // K = 4 chunks of 32
            int c = kc * 4 + quad;            // chunk index = k/8
            s8v a = As[ar * 16 + (c ^ (ar & 7))];
#pragma unroll
            for (int nb = 0; nb < 4; ++nb) {
                int br = nb * 16 + lane16;
                s8v b = Bs[br * 16 + (c ^ (br & 7))];
                acc[nb] = __builtin_amdgcn_mfma_f32_16x16x32_bf16(a, b, acc[nb], 0, 0, 0);
            }
        }

        // mask + running top-2 (masked entries fed as exactly NEGV)
#pragma unroll
        for (int nb = 0; nb < 4; ++nb) {
            int u = u0 + nb * 16 + lane16;
            int du = depth[u];
#pragma unroll
            for (int r = 0; r < 4; ++r) {
                float s = (du < dvr[r]) ? acc[nb][r] : NEGV;
                top2_merge(s, u, v1[r], i1[r], v2[r], i2[r]);
            }
        }
    }

    // butterfly merge across the 16 col-lanes (same quad = same rows)
#pragma unroll
    for (int m = 1; m < 16; m <<= 1) {
#pragma unroll
        for (int r = 0; r < 4; ++r) {
            float ov1 = __shfl_xor(v1[r], m, 64);
            int   oi1 = __shfl_xor(i1[r], m, 64);
            float ov2 = __shfl_xor(v2[r], m, 64);
            int   oi2 = __shfl_xor(i2[r], m, 64);
            top2_merge(ov1, oi1, v1[r], i1[r], v2[r], i2[r]);
            top2_merge(ov2, oi2, v1[r], i1[r], v2[r], i2[r]);
        }
    }
    if (lane16 == 0) {
#pragma unroll
        for (int r = 0; r < 4; ++r) {
            int grow = row0 + w * 16 + quad * 4 + r;
            size_t o = ((size_t)seg * NN + grow) * 2;
            pv[o] = v1[r]; pv[o + 1] = v2[r];
            pi[o] = i1[r]; pi[o + 1] = i2[r];
        }
    }
}

// ONE kernel writes ALL outputs (f32): per node v (one wave each), merge the
// 8 segment partials, emit vals/idx/edge_valid, then the inversion MLP.
__global__ __launch_bounds__(256) void k_final(const float* __restrict__ pv,
                                               const int* __restrict__ pi,
                                               const int* __restrict__ ntype,
                                               const int* __restrict__ ndepth,
                                               const float* __restrict__ A,
                                               const float* __restrict__ B,
                                               const float* __restrict__ Wi2,
                                               const float* __restrict__ bi2,
                                               float* __restrict__ out) {
    int tid = threadIdx.x;
    int lane = tid & 63;
    int v = blockIdx.x * 4 + (tid >> 6);

    float V1 = -3.4e38f, V2 = -3.4e38f;
    int I1 = 0x7fffffff, I2 = 0x7fffffff;
#pragma unroll
    for (int s = 0; s < SEG; ++s) {
        size_t o = ((size_t)s * NN + v) * 2;
        top2_merge(pv[o],     pi[o],     V1, I1, V2, I2);
        top2_merge(pv[o + 1], pi[o + 1], V1, I1, V2, I2);
    }

    if (lane == 0) {
        int tp = ntype[v];
        bool tv = (tp != 0) && (ndepth[v] > 0) && (V1 > -5.0e8f);  // NEG/2
        out[2 * NN + 2 * v]     = V1;
        out[2 * NN + 2 * v + 1] = V2;
        out[4 * NN + 2 * v]     = (float)I1;
        out[4 * NN + 2 * v + 1] = (float)I2;
        out[6 * NN + 2 * v]     = tv ? 1.f : 0.f;
        out[6 * NN + 2 * v + 1] = (tv && tp == 2) ? 1.f : 0.f;
    }

    // inversion MLP: logit = relu(A[u] + B[v]) . Wi2 + bi2, 2 elems per lane
    const float2* B2 = (const float2*)B;
    const float2* W2v = (const float2*)Wi2;
    float2 bv = B2[(size_t)v * 64 + lane];
    float2 wv = W2v[lane];
    float bias = bi2[0];
#pragma unroll
    for (int j = 0; j < 2; ++j) {
        int u = (j == 0) ? I1 : I2;
        u = min(max(u, 0), NN - 1);  // defensive clamp (no-op when correct)
        float2 av = ((const float2*)A)[(size_t)u * 64 + lane];
        float h0 = fmaxf(av.x + bv.x, 0.f);
        float h1 = fmaxf(av.y + bv.y, 0.f);
        float acc = fmaf(h0, wv.x, h1 * wv.y);
        for (int off = 32; off > 0; off >>= 1) acc += __shfl_down(acc, off);
        if (lane == 0) {
            float logit = acc + bias;
            out[2 * v + j] = 1.f / (1.f + expf(-logit));
        }
    }
}

extern "C" void kernel_launch(void* const* d_in, const int* in_sizes, int n_in,
                              void* d_out, int out_size, void* d_ws, size_t ws_size,
                              hipStream_t stream) {
    (void)in_sizes; (void)n_in; (void)out_size; (void)ws_size;
    const float* x   = (const float*)d_in[0];
    const float* z   = (const float*)d_in[1];
    const int* ntype = (const int*)d_in[2];
    const int* ndep  = (const int*)d_in[3];
    const int* eidx  = (const int*)d_in[4];
    const float* W1  = (const float*)d_in[5];
    const float* b1  = (const float*)d_in[6];
    const float* W2  = (const float*)d_in[7];
    const float* b2  = (const float*)d_in[8];
    const float* Wm1 = (const float*)d_in[9];
    const float* bm1 = (const float*)d_in[10];
    const float* Wm2 = (const float*)d_in[11];
    const float* bm2 = (const float*)d_in[12];
    const float* Wsm = (const float*)d_in[13];
    const float* Wtm = (const float*)d_in[14];
    const float* Wi1 = (const float*)d_in[15];
    const float* bi1 = (const float*)d_in[16];
    const float* Wi2 = (const float*)d_in[17];
    const float* bi2 = (const float*)d_in[18];
    float* out = (float*)d_out;

    const int* esrc = eidx;
    const int* edst = eidx + NE;

    // Workspace layout (floats), partials FIRST, big buffers LAST. ~20.6 MiB.
    float* ws = (float*)d_ws;
    float* pv   = ws;                                  // [SEG*2*NN]
    int*   pi   = (int*)(pv + (size_t)SEG * 2 * NN);   // [SEG*2*NN]
    int*   degi = (int*)(pv + (size_t)2 * SEG * 2 * NN);  // [N]
    float* inv  = (float*)degi + NN;                   // [N]
    float* agg2 = inv + NN;                            // [2N]
    float* cz1  = agg2 + 2 * NN;                       // [128]
    float* cz2  = cz1 + 128;                           // [128]
    size_t F = (size_t)NN * HD;
    float* s0 = cz2 + 128;   // h1 (f32) -> {ht_bf16, hs_bf16}
    float* s1 = s0 + F;      // aggH -> h2 -> t -> h -> B   (in-place chain)
    float* s2 = s1 + F;      // A = h @ Wi1[:128]
    __hip_bfloat16* htb = (__hip_bfloat16*)s0;       // [N*HD] bf16
    __hip_bfloat16* hsb = htb + F;                   // [N*HD] bf16

    k_deg_init<<<NN / 256, 256, 0, stream>>>(degi);
    k_deg_count<<<NE / 256, 256, 0, stream>>>(edst, degi);
    k_inv_agg2<<<NN / 256, 256, 0, stream>>>(degi, x, inv, agg2);
    k_scatter2<<<NE / 256, 256, 0, stream>>>(esrc, edst, x, inv, agg2);
    k_lin1<<<NN * HD / 256, 256, 0, stream>>>(agg2, W1, b1, inv, s0, s1);
    k_scatterH<<<NE / 2, 256, 0, stream>>>(esrc, edst, inv, s0, s1);
    k_zvec<<<1, 256, 0, stream>>>(z, Wm1, bm1, Wi1, bi1, cz1, cz2);
    k_rowmm<<<NN / 16, 256, 0, stream>>>(s1, W2, b2, s1, nullptr, 1);      // h2 (in-place)
    k_rowmm<<<NN / 16, 256, 0, stream>>>(s1, Wm1, cz1, s1, nullptr, 1);    // t  (in-place)
    k_rowmm<<<NN / 16, 256, 0, stream>>>(s1, Wm2, bm2, s1, nullptr, 0);    // h  (in-place)
    k_rowmm<<<NN / 16, 256, 0, stream>>>(s1, Wtm, nullptr, nullptr, htb, 0);  // ht (bf16)
    k_rowmm<<<NN / 16, 256, 0, stream>>>(s1, Wsm, nullptr, nullptr, hsb, 0);  // hs (bf16)
    k_score_top2_mfma<<<dim3(NN / 64, SEG), 256, 0, stream>>>(htb, hsb, ndep, pv, pi);
    k_rowmm<<<NN / 16, 256, 0, stream>>>(s1, Wi1, nullptr, s2, nullptr, 0);   // A
    k_rowmm<<<NN / 16, 256, 0, stream>>>(s1, Wi1 + HD * HD, cz2, s1, nullptr, 0);  // B (in-place)
    k_final<<<NN / 4, 256, 0, stream>>>(pv, pi, ntype, ndep, s2, s1, Wi2, bi2, out);
}

// Round 5
// 784.857 us; speedup vs baseline: 1.9275x; 1.0034x over previous
//
#include <hip/hip_runtime.h>
#include <hip/hip_bf16.h>

#define NN 12288
#define NE 196608
#define HD 128
#define ZD 128
#define NEGV (-1.0e9f)
#define SEG 8
#define SEG_U (NN / SEG)            // 1536
#define TILES_PER_SEG (SEG_U / 64)  // 24

using s8v = __attribute__((ext_vector_type(8))) short;  // 8 bf16 = 4 VGPRs
using f4v = __attribute__((ext_vector_type(4))) float;  // 4 fp32 acc

// Stable top-2 merge: total order by (value desc, index asc) — associative,
// reproduces jax.lax.top_k stable tie-breaking regardless of merge order.
__device__ __forceinline__ void top2_merge(float s, int u, float& v1, int& i1,
                                           float& v2, int& i2) {
    if (s > v1 || (s == v1 && u < i1)) { v2 = v1; i2 = i1; v1 = s; i1 = u; }
    else if (s > v2 || (s == v2 && u < i2)) { v2 = s; i2 = u; }
}

__global__ __launch_bounds__(256) void k_deg_init(int* degi) {
    int i = blockIdx.x * 256 + threadIdx.x;
    degi[i] = 1;  // self-loop
}

__global__ __launch_bounds__(256) void k_deg_count(const int* __restrict__ edst,
                                                   int* degi) {
    int e = blockIdx.x * 256 + threadIdx.x;
    atomicAdd(&degi[edst[e]], 1);
}

__global__ __launch_bounds__(256) void k_inv_agg2(const int* __restrict__ degi,
                                                  const float* __restrict__ x,
                                                  float* inv, float* agg2) {
    int i = blockIdx.x * 256 + threadIdx.x;
    float iv = rsqrtf((float)degi[i]);  // deg >= 1 always
    inv[i] = iv;
    float w = iv * iv;                  // self-loop weight
    agg2[2 * i]     = x[2 * i] * w;
    agg2[2 * i + 1] = x[2 * i + 1] * w;
}

__global__ __launch_bounds__(256) void k_scatter2(const int* __restrict__ esrc,
                                                  const int* __restrict__ edst,
                                                  const float* __restrict__ x,
                                                  const float* __restrict__ inv,
                                                  float* agg2) {
    int e = blockIdx.x * 256 + threadIdx.x;
    int u = esrc[e], v = edst[e];
    float w = inv[u] * inv[v];
    atomicAdd(&agg2[2 * v],     x[2 * u] * w);
    atomicAdd(&agg2[2 * v + 1], x[2 * u + 1] * w);
}

// h1 = relu(agg2 @ W1 + b1); also seed aggH with the layer-2 self-loop term.
__global__ __launch_bounds__(256) void k_lin1(const float* __restrict__ agg2,
                                              const float* __restrict__ W1,
                                              const float* __restrict__ b1,
                                              const float* __restrict__ inv,
                                              float* h1, float* aggH) {
    int t = blockIdx.x * 256 + threadIdx.x;
    int v = t >> 7, j = t & 127;
    float hv = fmaxf(fmaf(agg2[2 * v], W1[j],
                     fmaf(agg2[2 * v + 1], W1[HD + j], b1[j])), 0.f);
    h1[t] = hv;
    float iv = inv[v];
    aggH[t] = hv * iv * iv;
}

// 2 edges per 256-thread block; 128 lanes per edge; atomic scatter into aggH.
__global__ __launch_bounds__(256) void k_scatterH(const int* __restrict__ esrc,
                                                  const int* __restrict__ edst,
                                                  const float* __restrict__ inv,
                                                  const float* __restrict__ h1,
                                                  float* aggH) {
    int tid = threadIdx.x;
    int e = blockIdx.x * 2 + (tid >> 7);
    int j = tid & 127;
    int u = esrc[e], v = edst[e];
    float w = inv[u] * inv[v];
    atomicAdd(&aggH[(size_t)v * HD + j], h1[(size_t)u * HD + j] * w);
}

// cz1 = z @ Wm1[128:256] + bm1 ; cz2 = z @ Wi1[256:384] + bi1
__global__ __launch_bounds__(256) void k_zvec(const float* __restrict__ z,
                                              const float* __restrict__ Wm1,
                                              const float* __restrict__ bm1,
                                              const float* __restrict__ Wi1,
                                              const float* __restrict__ bi1,
                                              float* cz1, float* cz2) {
    int tid = threadIdx.x;
    int j = tid & 127;
    if (tid < 128) {
        float a = bm1[j];
        for (int k = 0; k < ZD; ++k) a = fmaf(z[k], Wm1[(HD + k) * HD + j], a);
        cz1[j] = a;
    } else {
        float a = bi1[j];
        for (int k = 0; k < ZD; ++k) a = fmaf(z[k], Wi1[(2 * HD + k) * HD + j], a);
        cz2[j] = a;
    }
}

// Generic N x 128 @ 128 x 128 (+bias)(+relu). 16 rows/block, 256 threads.
// IN-PLACE SAFE (out may equal in): each block stages its 16 rows into LDS
// before the barrier and only writes the rows it staged.
// If outb != nullptr, writes bf16 (rte) to outb instead of f32 to out.
__global__ __launch_bounds__(256) void k_rowmm(const float* __restrict__ in,
                                               const float* __restrict__ W,
                                               const float* __restrict__ bias,
                                               float* __restrict__ out,
                                               __hip_bfloat16* __restrict__ outb,
                                               int do_relu) {
    __shared__ float4 ins4[16 * 32];
    int tid = threadIdx.x;
    int r0 = blockIdx.x * 16;
    const float4* src4 = (const float4*)(in + (size_t)r0 * HD);
#pragma unroll
    for (int i = 0; i < 2; ++i) ins4[tid + i * 256] = src4[tid + i * 256];
    __syncthreads();
    int j = tid & 127;
    int rg = tid >> 7;  // 0..1
    float acc[8];
#pragma unroll
    for (int r = 0; r < 8; ++r) acc[r] = 0.f;
    for (int k4 = 0; k4 < 32; ++k4) {
        int k = k4 * 4;
        float w0 = W[(k + 0) * HD + j];
        float w1 = W[(k + 1) * HD + j];
        float w2 = W[(k + 2) * HD + j];
        float w3 = W[(k + 3) * HD + j];
#pragma unroll
        for (int r = 0; r < 8; ++r) {
            float4 iv = ins4[(rg * 8 + r) * 32 + k4];
            acc[r] = fmaf(iv.x, w0, acc[r]);
            acc[r] = fmaf(iv.y, w1, acc[r]);
            acc[r] = fmaf(iv.z, w2, acc[r]);
            acc[r] = fmaf(iv.w, w3, acc[r]);
        }
    }
    float bv = bias ? bias[j] : 0.f;
#pragma unroll
    for (int r = 0; r < 8; ++r) {
        float v = acc[r] + bv;
        if (do_relu) v = fmaxf(v, 0.f);
        size_t o = (size_t)(r0 + rg * 8 + r) * HD + j;
        if (outb) outb[o] = __float2bfloat16(v);
        else      out[o] = v;
    }
}

// Fused bf16-MFMA scores + masked stable top-2, v2.
// Key changes vs v1 (which showed 426 MB phantom HBM writes — suspected
// scratch lowering of ext-vector LDS staging):
//  * A fragments are loop-invariant -> loaded ONCE from global into regs;
//    no A tile in LDS at all.
//  * B staged as plain float4 (r3-proven codegen); bit_cast to s8v only on
//    the register value at the MFMA call.
//  * LDS double-buffer (2 x 16 KB) + register prefetch: ONE barrier/tile,
//    tile t+1's global loads in flight during tile t's MFMA+merge.
// mfma_f32_16x16x32_bf16 layouts (HW-verified m89/m91/m120):
//   A[m=lane&15][k=(lane>>4)*8+j]; B^T[n=lane&15][k=...] (hs row-major);
//   C/D: col(n)=lane&15, row(m)=(lane>>4)*4+reg.
__global__ __launch_bounds__(256) void k_score_top2_mfma(
        const __hip_bfloat16* __restrict__ htb,
        const __hip_bfloat16* __restrict__ hsb,
        const int* __restrict__ depth,
        float* __restrict__ pv, int* __restrict__ pi) {
    __shared__ float4 Bs[2][64 * 16];  // 2 x 16 KB
    int tid = threadIdx.x;
    int w = tid >> 6;       // wave -> m-block (16 target rows)
    int l = tid & 63;
    int lane16 = l & 15;
    int quad = l >> 4;      // 0..3
    int row0 = blockIdx.x * 64;
    int seg = blockIdx.y;
    int u_base = seg * SEG_U;

    // A fragments (registers, loop-invariant): row = w*16+lane16,
    // chunk index c = kc*4+quad (8 bf16 = 16 B each).
    s8v afrag[4];
    {
        const float4* ga = (const float4*)(htb + (size_t)(row0 + w * 16 + lane16) * HD);
#pragma unroll
        for (int kc = 0; kc < 4; ++kc)
            afrag[kc] = __builtin_bit_cast(s8v, ga[kc * 4 + quad]);
    }

    int dvr[4];  // depths of the 4 C rows this lane owns (row = quad*4+r)
#pragma unroll
    for (int r = 0; r < 4; ++r) dvr[r] = depth[row0 + w * 16 + quad * 4 + r];

    float v1[4], v2[4];
    int i1[4], i2[4];
#pragma unroll
    for (int r = 0; r < 4; ++r) {
        v1[r] = v2[r] = -3.4e38f;
        i1[r] = i2[r] = 0x7fffffff;
    }

    // stage tile 0 into buf 0 (swizzled: [row*16 + (c ^ (row&7))])
    float4 pre[4];
    {
        const float4* g = (const float4*)(hsb + (size_t)u_base * HD);
#pragma unroll
        for (int i = 0; i < 4; ++i) pre[i] = g[tid + i * 256];
#pragma unroll
        for (int i = 0; i < 4; ++i) {
            int q = tid + i * 256;
            int r = q >> 4, c = q & 15;
            Bs[0][r * 16 + (c ^ (r & 7))] = pre[i];
        }
    }

    for (int t = 0; t < TILES_PER_SEG; ++t) {
        int u0 = u_base + t * 64;
        __syncthreads();  // buf[t&1] fully written; buf[(t+1)&1] fully consumed

        if (t + 1 < TILES_PER_SEG) {  // prefetch tile t+1 into regs
            const float4* g = (const float4*)(hsb + (size_t)(u0 + 64) * HD);
#pragma unroll
            for (int i = 0; i < 4; ++i) pre[i] = g[tid + i * 256];
        }

        const float4* B = Bs[t & 1];
        f4v acc[4];
#pragma unroll
        for (int nb = 0; nb < 4; ++nb) acc[nb] = (f4v){0.f, 0.f, 0.f, 0.f};

#pragma unroll
        for (int kc = 0; kc < 4; ++kc) {      // K = 4 chunks of 32
            int c = kc * 4 + quad;
#pragma unroll
            for (int nb = 0; nb < 4; ++nb) {
                int br = nb * 16 + lane16;
                s8v b = __builtin_bit_cast(s8v, B[br * 16 + (c ^ (br & 7))]);
                acc[nb] = __builtin_amdgcn_mfma_f32_16x16x32_bf16(afrag[kc], b, acc[nb], 0, 0, 0);
            }
        }

        // mask + running top-2 (masked entries fed as exactly NEGV)
#pragma unroll
        for (int nb = 0; nb < 4; ++nb) {
            int u = u0 + nb * 16 + lane16;
            int du = depth[u];
#pragma unroll
            for (int r = 0; r < 4; ++r) {
                float s = (du < dvr[r]) ? acc[nb][r] : NEGV;
                top2_merge(s, u, v1[r], i1[r], v2[r], i2[r]);
            }
        }

        if (t + 1 < TILES_PER_SEG) {  // write prefetched tile into other buf
            float4* Bn = Bs[(t + 1) & 1];
#pragma unroll
            for (int i = 0; i < 4; ++i) {
                int q = tid + i * 256;
                int r = q >> 4, c = q & 15;
                Bn[r * 16 + (c ^ (r & 7))] = pre[i];
            }
        }
    }

    // butterfly merge across the 16 col-lanes (same quad = same rows)
#pragma unroll
    for (int m = 1; m < 16; m <<= 1) {
#pragma unroll
        for (int r = 0; r < 4; ++r) {
            float ov1 = __shfl_xor(v1[r], m, 64);
            int   oi1 = __shfl_xor(i1[r], m, 64);
            float ov2 = __shfl_xor(v2[r], m, 64);
            int   oi2 = __shfl_xor(i2[r], m, 64);
            top2_merge(ov1, oi1, v1[r], i1[r], v2[r], i2[r]);
            top2_merge(ov2, oi2, v1[r], i1[r], v2[r], i2[r]);
        }
    }
    if (lane16 == 0) {
#pragma unroll
        for (int r = 0; r < 4; ++r) {
            int grow = row0 + w * 16 + quad * 4 + r;
            size_t o = ((size_t)seg * NN + grow) * 2;
            pv[o] = v1[r]; pv[o + 1] = v2[r];
            pi[o] = i1[r]; pi[o + 1] = i2[r];
        }
    }
}

// ONE kernel writes ALL outputs (f32): per node v (one wave each), merge the
// 8 segment partials, emit vals/idx/edge_valid, then the inversion MLP.
__global__ __launch_bounds__(256) void k_final(const float* __restrict__ pv,
                                               const int* __restrict__ pi,
                                               const int* __restrict__ ntype,
                                               const int* __restrict__ ndepth,
                                               const float* __restrict__ A,
                                               const float* __restrict__ B,
                                               const float* __restrict__ Wi2,
                                               const float* __restrict__ bi2,
                                               float* __restrict__ out) {
    int tid = threadIdx.x;
    int lane = tid & 63;
    int v = blockIdx.x * 4 + (tid >> 6);

    float V1 = -3.4e38f, V2 = -3.4e38f;
    int I1 = 0x7fffffff, I2 = 0x7fffffff;
#pragma unroll
    for (int s = 0; s < SEG; ++s) {
        size_t o = ((size_t)s * NN + v) * 2;
        top2_merge(pv[o],     pi[o],     V1, I1, V2, I2);
        top2_merge(pv[o + 1], pi[o + 1], V1, I1, V2, I2);
    }

    if (lane == 0) {
        int tp = ntype[v];
        bool tv = (tp != 0) && (ndepth[v] > 0) && (V1 > -5.0e8f);  // NEG/2
        out[2 * NN + 2 * v]     = V1;
        out[2 * NN + 2 * v + 1] = V2;
        out[4 * NN + 2 * v]     = (float)I1;
        out[4 * NN + 2 * v + 1] = (float)I2;
        out[6 * NN + 2 * v]     = tv ? 1.f : 0.f;
        out[6 * NN + 2 * v + 1] = (tv && tp == 2) ? 1.f : 0.f;
    }

    // inversion MLP: logit = relu(A[u] + B[v]) . Wi2 + bi2, 2 elems per lane
    const float2* B2 = (const float2*)B;
    const float2* W2v = (const float2*)Wi2;
    float2 bv = B2[(size_t)v * 64 + lane];
    float2 wv = W2v[lane];
    float bias = bi2[0];
#pragma unroll
    for (int j = 0; j < 2; ++j) {
        int u = (j == 0) ? I1 : I2;
        u = min(max(u, 0), NN - 1);  // defensive clamp (no-op when correct)
        float2 av = ((const float2*)A)[(size_t)u * 64 + lane];
        float h0 = fmaxf(av.x + bv.x, 0.f);
        float h1 = fmaxf(av.y + bv.y, 0.f);
        float acc = fmaf(h0, wv.x, h1 * wv.y);
        for (int off = 32; off > 0; off >>= 1) acc += __shfl_down(acc, off);
        if (lane == 0) {
            float logit = acc + bias;
            out[2 * v + j] = 1.f / (1.f + expf(-logit));
        }
    }
}

extern "C" void kernel_launch(void* const* d_in, const int* in_sizes, int n_in,
                              void* d_out, int out_size, void* d_ws, size_t ws_size,
                              hipStream_t stream) {
    (void)in_sizes; (void)n_in; (void)out_size; (void)ws_size;
    const float* x   = (const float*)d_in[0];
    const float* z   = (const float*)d_in[1];
    const int* ntype = (const int*)d_in[2];
    const int* ndep  = (const int*)d_in[3];
    const int* eidx  = (const int*)d_in[4];
    const float* W1  = (const float*)d_in[5];
    const float* b1  = (const float*)d_in[6];
    const float* W2  = (const float*)d_in[7];
    const float* b2  = (const float*)d_in[8];
    const float* Wm1 = (const float*)d_in[9];
    const float* bm1 = (const float*)d_in[10];
    const float* Wm2 = (const float*)d_in[11];
    const float* bm2 = (const float*)d_in[12];
    const float* Wsm = (const float*)d_in[13];
    const float* Wtm = (const float*)d_in[14];
    const float* Wi1 = (const float*)d_in[15];
    const float* bi1 = (const float*)d_in[16];
    const float* Wi2 = (const float*)d_in[17];
    const float* bi2 = (const float*)d_in[18];
    float* out = (float*)d_out;

    const int* esrc = eidx;
    const int* edst = eidx + NE;

    // Workspace layout (floats), partials FIRST, big buffers LAST. ~20.6 MiB.
    float* ws = (float*)d_ws;
    float* pv   = ws;                                  // [SEG*2*NN]
    int*   pi   = (int*)(pv + (size_t)SEG * 2 * NN);   // [SEG*2*NN]
    int*   degi = (int*)(pv + (size_t)2 * SEG * 2 * NN);  // [N]
    float* inv  = (float*)degi + NN;                   // [N]
    float* agg2 = inv + NN;                            // [2N]
    float* cz1  = agg2 + 2 * NN;                       // [128]
    float* cz2  = cz1 + 128;                           // [128]
    size_t F = (size_t)NN * HD;
    float* s0 = cz2 + 128;   // h1 (f32) -> {ht_bf16, hs_bf16}
    float* s1 = s0 + F;      // aggH -> h2 -> t -> h -> B   (in-place chain)
    float* s2 = s1 + F;      // A = h @ Wi1[:128]
    __hip_bfloat16* htb = (__hip_bfloat16*)s0;       // [N*HD] bf16
    __hip_bfloat16* hsb = htb + F;                   // [N*HD] bf16

    k_deg_init<<<NN / 256, 256, 0, stream>>>(degi);
    k_deg_count<<<NE / 256, 256, 0, stream>>>(edst, degi);
    k_inv_agg2<<<NN / 256, 256, 0, stream>>>(degi, x, inv, agg2);
    k_scatter2<<<NE / 256, 256, 0, stream>>>(esrc, edst, x, inv, agg2);
    k_lin1<<<NN * HD / 256, 256, 0, stream>>>(agg2, W1, b1, inv, s0, s1);
    k_scatterH<<<NE / 2, 256, 0, stream>>>(esrc, edst, inv, s0, s1);
    k_zvec<<<1, 256, 0, stream>>>(z, Wm1, bm1, Wi1, bi1, cz1, cz2);
    k_rowmm<<<NN / 16, 256, 0, stream>>>(s1, W2, b2, s1, nullptr, 1);      // h2 (in-place)
    k_rowmm<<<NN / 16, 256, 0, stream>>>(s1, Wm1, cz1, s1, nullptr, 1);    // t  (in-place)
    k_rowmm<<<NN / 16, 256, 0, stream>>>(s1, Wm2, bm2, s1, nullptr, 0);    // h  (in-place)
    k_rowmm<<<NN / 16, 256, 0, stream>>>(s1, Wtm, nullptr, nullptr, htb, 0);  // ht (bf16)
    k_rowmm<<<NN / 16, 256, 0, stream>>>(s1, Wsm, nullptr, nullptr, hsb, 0);  // hs (bf16)
    k_score_top2_mfma<<<dim3(NN / 64, SEG), 256, 0, stream>>>(htb, hsb, ndep, pv, pi);
    k_rowmm<<<NN / 16, 256, 0, stream>>>(s1, Wi1, nullptr, s2, nullptr, 0);   // A
    k_rowmm<<<NN / 16, 256, 0, stream>>>(s1, Wi1 + HD * HD, cz2, s1, nullptr, 0);  // B (in-place)
    k_final<<<NN / 4, 256, 0, stream>>>(pv, pi, ntype, ndep, s2, s1, Wi2, bi2, out);
}